// Round 2
// 409.821 us; speedup vs baseline: 1.0336x; 1.0336x over previous
//
#include <hip/hip_runtime.h>
#include <hip/hip_bf16.h>

#define RMAX 40
#define LK   81
#define HH   512
#define WW   512
#define CC   3
#define BB   64
#define ROWS 2    // h-rows per passB block

typedef unsigned short u16;
typedef __attribute__((ext_vector_type(8))) short short8;   // 8 bf16 (4 VGPR) MFMA A/B frag
typedef __attribute__((ext_vector_type(4))) float f32x4;    // MFMA C/D frag

// bf16 round-to-nearest-even pack/unpack (values here are finite, no NaN)
__device__ __forceinline__ u16 f2bf(float f) {
    unsigned u = __float_as_uint(f);
    u += 0x7FFFu + ((u >> 16) & 1u);
    return (u16)(u >> 16);
}
__device__ __forceinline__ float bf2f(u16 s) {
    return __uint_as_float(((unsigned)s) << 16);
}

// ---------------------------------------------------------------------------
// Kernel A (prep), 64 blocks x 256 threads (one block per sample b):
//  - wbuf  [64][128]: zero-padded fp32 taps for passB (tap p at index 56+p)
//  - mbuf  [64][12]:  3x3 channel-mix matrix (C-axis conv through reflect-3)
//  - rbuf  [64]:      per-sample radius
//  - atab  [64][16 slots][64 lanes][8]: bf16 Toeplitz A-fragments for passC's
//    MFMA H-conv. slot s = ch*4 + half*2 + prec; A[i][kk] = kz[32*ch + kk - i
//    - 16*half], lane i = lane&15, kk = 8*(lane>>4)+j. prec0 = bf16(w) ("hi"),
//    prec1 = bf16(w - hi) ("lo") so hi+lo carries fp32-grade weights.
// ---------------------------------------------------------------------------
__global__ __launch_bounds__(256) void prep_kernel(
    const float* __restrict__ sigmas10,
    const int*   __restrict__ steps,
    int*   __restrict__ rbuf,
    float* __restrict__ mbuf,
    float* __restrict__ wbuf,
    u16*   __restrict__ atab)
{
    const int b   = blockIdx.x;
    const int tid = threadIdx.x;
    const float sigma = sigmas10[steps[b]];
    int r = (int)floorf(4.0f * sigma + 0.5f);
    if (r > RMAX) r = RMAX;
    const float s2 = sigma * sigma;

    float sum = 0.0f;
    for (int p = -r; p <= r; ++p)
        sum += expf(-0.5f * (float)(p * p) / s2);
    const float inv = 1.0f / sum;

    // fp32 taps for passB (identical layout/values to previous version)
    if (tid < 128) {
        int p = tid - 56;                      // index 16 + (p + RMAX)
        float v = 0.0f;
        if (p >= -r && p <= r)
            v = expf(-0.5f * (float)(p * p) / s2) * inv;
        wbuf[b * 128 + tid] = v;
    }

    if (tid == 0) {
        rbuf[b] = r;
        float Mm[9];
        for (int i = 0; i < 9; ++i) Mm[i] = 0.0f;
        for (int p = -r; p <= r; ++p) {
            float wv = expf(-0.5f * (float)(p * p) / s2) * inv;
            for (int c = 0; c < CC; ++c) {
                int i = c + p;
                int j = ((i % 6) + 6) % 6;     // reflect for n=3 -> period 6
                int cc = (j < 3) ? j : 5 - j;
                Mm[c * 3 + cc] += wv;
            }
        }
        for (int c = 0; c < 3; ++c)
            for (int cc = 0; cc < 3; ++cc)
                mbuf[b * 12 + c * 4 + cc] = Mm[c * 3 + cc];
    }

    // A-fragment table: 16 slots x 64 lanes x 8 = 8192 bf16 per sample
    u16* ab = atab + (size_t)b * 8192;
    int e = tid * 32;
    for (int ee = 0; ee < 32; ++ee, ++e) {
        int j    = e & 7;
        int lane = (e >> 3) & 63;
        int s    = e >> 9;          // 0..15
        int ch   = s >> 2;          // 0..3   (K-chunk of 32 rows)
        int half = (s >> 1) & 1;    // output h-half (i or i+16)
        int prec = s & 1;           // 0=hi, 1=lo
        int m = 32 * ch + ((lane >> 4) << 3) + j - (lane & 15) - 16 * half;
        float wfull = 0.0f;
        if (m >= 0 && m <= 2 * r) {
            int p = m - r;
            wfull = expf(-0.5f * (float)(p * p) / s2) * inv;
        }
        u16 hi = f2bf(wfull);
        u16 val = hi;
        if (prec) val = f2bf(wfull - bf2f(hi));
        ab[e] = val;
    }
}

// ---------------------------------------------------------------------------
// Kernel B: fused channel mix + W-axis conv, bf16 output. (unchanged)
// One block per (b, 2 h-rows), 256 threads, LDS 14.2 KB -> 8 blocks/CU.
// ---------------------------------------------------------------------------
__global__ __launch_bounds__(256) void passB_kernel(
    const float* __restrict__ x,
    const float* __restrict__ wbuf,
    const float* __restrict__ mbuf,
    const int*   __restrict__ rbuf,
    u16* __restrict__ out1)
{
    __shared__ __align__(16) float mixed[CC * ROWS][WW + 2 * RMAX]; // [6][592]

    const int b   = blockIdx.y;
    const int h0  = blockIdx.x * ROWS;
    const int tid = threadIdx.x;
    const int r   = __builtin_amdgcn_readfirstlane(rbuf[b]);

    const float M00 = mbuf[b * 12 + 0], M01 = mbuf[b * 12 + 1], M02 = mbuf[b * 12 + 2];
    const float M10 = mbuf[b * 12 + 4], M11 = mbuf[b * 12 + 5], M12 = mbuf[b * 12 + 6];
    const float M20 = mbuf[b * 12 + 8], M21 = mbuf[b * 12 + 9], M22 = mbuf[b * 12 + 10];

    const float* xb = x + (size_t)b * CC * HH * WW + (size_t)h0 * WW;

    for (int idx = tid; idx < WW + 2 * RMAX; idx += 256) {
        int i  = idx - RMAX;                 // logical position -40..551
        int jm = i & (2 * WW - 1);           // mod 1024 (ok for negatives)
        int src = (jm < WW) ? jm : (2 * WW - 1 - jm);
        float a0 = __builtin_nontemporal_load(xb + src);
        float a1 = __builtin_nontemporal_load(xb + HH * WW + src);
        float a2 = __builtin_nontemporal_load(xb + 2 * HH * WW + src);
        float b0 = __builtin_nontemporal_load(xb + WW + src);
        float b1 = __builtin_nontemporal_load(xb + HH * WW + WW + src);
        float b2 = __builtin_nontemporal_load(xb + 2 * HH * WW + WW + src);
        mixed[0][idx] = M00 * a0 + M01 * a1 + M02 * a2;  // c=0,row=0
        mixed[1][idx] = M00 * b0 + M01 * b1 + M02 * b2;  // c=0,row=1
        mixed[2][idx] = M10 * a0 + M11 * a1 + M12 * a2;  // c=1,row=0
        mixed[3][idx] = M10 * b0 + M11 * b1 + M12 * b2;  // c=1,row=1
        mixed[4][idx] = M20 * a0 + M21 * a1 + M22 * a2;  // c=2,row=0
        mixed[5][idx] = M20 * b0 + M21 * b1 + M22 * b2;  // c=2,row=1
    }
    __syncthreads();

    const int t0    = (RMAX - r) & ~3;                  // aligned first tap
    const int n4    = ((r + RMAX + 3 - t0) >> 2) + 1;   // float4 iterations
    const int kbase = (16 + t0) >> 2;
    const float4* K4 = (const float4*)(wbuf + b * 128);

#pragma unroll
    for (int k = 0; k < 3; ++k) {
        const int task = tid + 256 * k;     // 0..767
        const int g    = task & 127;
        const int rc   = task >> 7;         // 0..5  (c = rc>>1, row = rc&1)
        const int w0   = g << 2;

        const int dbase = (w0 + t0) >> 2;
        const float4* D4 = (const float4*)(&mixed[rc][0]);

        float4 Wlo = K4[kbase - 1];
        float acc0 = 0.f, acc1 = 0.f, acc2 = 0.f, acc3 = 0.f;

        for (int s = 0; s < n4; ++s) {
            float4 Whi = K4[kbase + s];     // uniform -> scalar load
            float4 D   = D4[dbase + s];     // ds_read_b128, conflict-free
            acc0 += Whi.x * D.x; acc1 += Wlo.w * D.x; acc2 += Wlo.z * D.x; acc3 += Wlo.y * D.x;
            acc0 += Whi.y * D.y; acc1 += Whi.x * D.y; acc2 += Wlo.w * D.y; acc3 += Wlo.z * D.y;
            acc0 += Whi.z * D.z; acc1 += Whi.y * D.z; acc2 += Whi.x * D.z; acc3 += Wlo.w * D.z;
            acc0 += Whi.w * D.w; acc1 += Whi.z * D.w; acc2 += Whi.y * D.w; acc3 += Whi.x * D.w;
            Wlo = Whi;
        }

        ushort4 o;
        o.x = f2bf(acc0); o.y = f2bf(acc1); o.z = f2bf(acc2); o.w = f2bf(acc3);
        const int c = rc >> 1, row = rc & 1;
        u16* dst = out1 + ((size_t)b * CC + c) * HH * WW
                 + (size_t)(h0 + row) * WW + w0;
        *(ushort4*)dst = o;                  // 8B aligned (w0 % 4 == 0)
    }
}

// ---------------------------------------------------------------------------
// Kernel C: H-axis conv as MFMA. The conv is a banded matmul
//   out[h0+i][w] = sum_t kz[t-i] * inter[h0-r+t][w]
// i.e. D = A*B with A = per-sample Toeplitz (precomputed lane-exact in atab,
// hi+lo bf16 pair for fp32-grade weights) and B = inter rows (already bf16).
// One block = 4 independent waves; wave = one 16-wide w tile x 32 h outputs
// (two 16x16 C tiles, half0/half1, sharing the same B fragments).
// Per K-chunk of 32 rows: 8 row-strided ushort loads (B frag), 4 coalesced
// dwordx4 loads (A frags), 4 MFMAs. No LDS, no barriers.
// ---------------------------------------------------------------------------
__device__ __forceinline__ int refl512(int i) {
    int jm = i & (2 * HH - 1);              // mod 1024, ok for i >= -1024
    return (jm < HH) ? jm : (2 * HH - 1 - jm);
}

__global__ __launch_bounds__(256) void passC_kernel(
    const u16* __restrict__ in1,
    const u16* __restrict__ atab,
    const int* __restrict__ rbuf,
    float* __restrict__ out)
{
    const int tid  = threadIdx.x;
    const int lane = tid & 63;
    const int bc   = blockIdx.z;            // b*3 + c
    const int b    = bc / 3;
    const int r    = __builtin_amdgcn_readfirstlane(rbuf[b]);
    const int h0   = blockIdx.y * 32;
    const int w    = blockIdx.x * 64 + (tid >> 6) * 16 + (lane & 15);
    const int nch  = (2 * r + 63) >> 5;     // ceil((2r+32)/32), 2..4
    const int rowbase = h0 - r + ((lane >> 4) << 3);

    const u16* src = in1 + (size_t)bc * HH * WW + w;
    const short8* at = (const short8*)(atab + (size_t)b * 8192);

    f32x4 acc0 = {0.f, 0.f, 0.f, 0.f};
    f32x4 acc1 = {0.f, 0.f, 0.f, 0.f};

    for (int ch = 0; ch < nch; ++ch) {
        // B fragment: 8 consecutive K-rows (this lane's k-group) at column w
        short8 bv;
#pragma unroll
        for (int j = 0; j < 8; ++j) {
            int row = refl512(rowbase + 32 * ch + j);
            bv[j] = (short)src[(size_t)row * WW];
        }
        // A fragments: slot = ch*4 + half*2 + prec, lane-indexed 16B each
        short8 ah0 = at[(ch * 4 + 0) * 64 + lane];
        short8 al0 = at[(ch * 4 + 1) * 64 + lane];
        short8 ah1 = at[(ch * 4 + 2) * 64 + lane];
        short8 al1 = at[(ch * 4 + 3) * 64 + lane];

        acc0 = __builtin_amdgcn_mfma_f32_16x16x32_bf16(ah0, bv, acc0, 0, 0, 0);
        acc0 = __builtin_amdgcn_mfma_f32_16x16x32_bf16(al0, bv, acc0, 0, 0, 0);
        acc1 = __builtin_amdgcn_mfma_f32_16x16x32_bf16(ah1, bv, acc1, 0, 0, 0);
        acc1 = __builtin_amdgcn_mfma_f32_16x16x32_bf16(al1, bv, acc1, 0, 0, 0);
    }

    // C/D layout: col = lane&15 (== our w), row = 4*(lane>>4) + reg
    const int orow = h0 + ((lane >> 4) << 2);
    float* dst = out + (size_t)bc * HH * WW + (size_t)orow * WW + w;
#pragma unroll
    for (int q = 0; q < 4; ++q) {
        __builtin_nontemporal_store(acc0[q], dst + (size_t)q * WW);
        __builtin_nontemporal_store(acc1[q], dst + (size_t)(q + 16) * WW);
    }
}

// ---------------------------------------------------------------------------
extern "C" void kernel_launch(void* const* d_in, const int* in_sizes, int n_in,
                              void* d_out, int out_size, void* d_ws, size_t ws_size,
                              hipStream_t stream)
{
    const float* x      = (const float*)d_in[0];
    const float* sigmas = (const float*)d_in[1];
    const int*   steps  = (const int*)d_in[2];
    float*       out    = (float*)d_out;

    int*   rbuf  = (int*)d_ws;                              // 256 B
    float* mbuf  = (float*)((char*)d_ws + 256);             // 3 KB
    float* wbuf  = (float*)((char*)d_ws + 4096);            // 32 KB
    u16*   atab  = (u16*)((char*)d_ws + 65536);             // 1 MiB A-frag table
    u16*   inter = (u16*)((char*)d_ws + 65536 + (1 << 20)); // 96 MiB bf16

    prep_kernel<<<64, 256, 0, stream>>>(sigmas, steps, rbuf, mbuf, wbuf, atab);

    dim3 gB(HH / ROWS, BB);
    passB_kernel<<<gB, 256, 0, stream>>>(x, wbuf, mbuf, rbuf, inter);

    dim3 gC(WW / 64, HH / 32, BB * CC);
    passC_kernel<<<gC, 256, 0, stream>>>(inter, atab, rbuf, out);
}